// Round 4
// baseline (283.839 us; speedup 1.0000x reference)
//
#include <hip/hip_runtime.h>

namespace {

constexpr int B  = 16;
constexpr int D  = 128;
constexpr int C  = 6;
constexpr int H  = 128;
constexpr int W  = 128;
constexpr int HWC = H * W;          // 16384
constexpr int HO = 512, WO = 512;   // 4x upsample
constexpr int TILE = 64;            // pixels per LDS tile
constexpr int TPB  = 8;             // tiles per block (block owns 512 contiguous px)
constexpr int NBLK = HWC / (TILE * TPB);  // 32 blocks per batch image

// ---------------------------------------------------------------------------
// Fused K1+K2, double-buffered: one HBM pass over assp, loads for tile t+1
// in flight (VGPRs) while tile t is consumed from LDS. 2 syncs/tile.
// Per 64-px tile (XOR-swizzled LDS, <=2-way banks both access patterns):
//   2a: px-ownership dots -> argmax class (register) + x = dot/12 + bias
//   2b: d-ownership per-class sums, accumulated in registers across 8 tiles
// Block-end: plain stores to partials[b][blk][C][D] + pcnt[b][blk][C]
// (no atomics, no memset). softmax(...,1).mean(1) == 1/12 -> attention dead.
// ---------------------------------------------------------------------------
__global__ __launch_bounds__(256) void k_fused(const float* __restrict__ assp,
                                               const float* __restrict__ cls_w,
                                               const float* __restrict__ cls_b,
                                               float* __restrict__ partials,
                                               int* __restrict__ pcnt,
                                               float* __restrict__ x) {
  __shared__ float buf[2][D * TILE];    // 2 x 32 KB, [d*64 + (px ^ (d&62))]
  __shared__ float red[4 * C * TILE];   // red[q][c][px], 6 KB (reused as part[])
  __shared__ float ws[C * D];
  __shared__ float bs[C];

  const int t  = threadIdx.x;
  const int b  = blockIdx.y;

  const int lane = t & 63;
  const int wv   = t >> 6;        // d-quarter for 2a, wave id
  const int d2b  = t & 127;       // d owned in 2b
  const int h2b  = t >> 7;        // px-half owned in 2b
  const int d1   = t >> 5;        // base d row for staging
  const int px2  = (t & 31) * 2;  // px pair for staging

  const float* base0 = assp + ((size_t)b * D) * HWC + blockIdx.x * (TILE * TPB);

  // prefetch tile 0 first — get HBM loads in flight before LDS staging of ws
  float2 v[16];
#pragma unroll
  for (int j = 0; j < 16; ++j) {
    int d = d1 + 8 * j;
    v[j] = *(const float2*)(base0 + (size_t)d * HWC + px2);
  }

  for (int i = t; i < C * D; i += 256) ws[i] = cls_w[i];
  if (t < C) bs[t] = cls_b[t];

  float acc2b[C] = {0.f, 0.f, 0.f, 0.f, 0.f, 0.f};
  int   cnt_run  = 0;             // wave0 lane c accumulates count of class c

  __syncthreads();                // ws/bs ready

  for (int it = 0; it < TPB; ++it) {
    float* cur = buf[it & 1];

    // ---- commit prefetched registers to LDS (swizzled) ----
#pragma unroll
    for (int j = 0; j < 16; ++j) {
      int d = d1 + 8 * j;
      *(float2*)&cur[d * TILE + (px2 ^ (d & 62))] = v[j];
    }
    // ---- issue next tile's global loads (overlap with compute below) ----
    if (it + 1 < TPB) {
      const float* basen = base0 + (it + 1) * TILE;
#pragma unroll
      for (int j = 0; j < 16; ++j) {
        int d = d1 + 8 * j;
        v[j] = *(const float2*)(basen + (size_t)d * HWC + px2);
      }
    }
    __syncthreads();              // staging of cur visible; red of prev iter free

    // ---- phase 2a: dots (px = lane, d-quarter = wv) ----
    {
      float a[C] = {0.f, 0.f, 0.f, 0.f, 0.f, 0.f};
#pragma unroll
      for (int dd = 0; dd < 32; ++dd) {
        int d = wv * 32 + dd;
        float vv = cur[d * TILE + (lane ^ (d & 62))];
#pragma unroll
        for (int c = 0; c < C; ++c) a[c] += vv * ws[c * D + d];
      }
#pragma unroll
      for (int c = 0; c < C; ++c) red[(wv * C + c) * TILE + lane] = a[c];
    }
    __syncthreads();

    // ---- finalize (replicated in all waves): class of px = lane ----
    int cls;
    {
      float s[C];
#pragma unroll
      for (int c = 0; c < C; ++c)
        s[c] = red[(0 * C + c) * TILE + lane] + red[(1 * C + c) * TILE + lane]
             + red[(2 * C + c) * TILE + lane] + red[(3 * C + c) * TILE + lane];
      float bv = s[0] + bs[0]; cls = 0;      // first-wins == jnp.argmax
#pragma unroll
      for (int c = 1; c < C; ++c) {
        float pv = s[c] + bs[c];
        if (pv > bv) { bv = pv; cls = c; }
      }
      if (wv == 0) {
        const float inv12 = 1.0f / 12.0f;
        int hw0 = blockIdx.x * (TILE * TPB) + it * TILE;
        float* xb = x + ((size_t)b * C) * HWC + hw0 + lane;
#pragma unroll
        for (int c = 0; c < C; ++c) xb[(size_t)c * HWC] = s[c] * inv12 + bs[c];
#pragma unroll
        for (int c = 0; c < C; ++c) {
          unsigned long long m = __ballot(cls == c);
          if (lane == c) cnt_run += (int)__popcll(m);
        }
      }
    }

    // ---- phase 2b: per-class sums (d = d2b, px-half = h2b) ----
#pragma unroll
    for (int i = 0; i < 32; ++i) {
      int px = h2b * 32 + i;
      float vv = cur[d2b * TILE + (px ^ (d2b & 62))];
      int c = __shfl(cls, px, 64);           // broadcast cls(px)
#pragma unroll
      for (int cc = 0; cc < C; ++cc) acc2b[cc] += (c == cc) ? vv : 0.f;
    }
    // no sync here: next iter writes the OTHER buffer; sync#1 of next iter
    // orders red reuse, and buf[x] writes are 2 syncs downstream of its reads
  }

  // ---- block epilogue: pair-reduce halves, plain stores (no atomics) ----
  __syncthreads();
  float* part = red;                          // reuse (>=768 floats)
  if (h2b == 1) {
#pragma unroll
    for (int c = 0; c < C; ++c) part[c * D + d2b] = acc2b[c];
  }
  __syncthreads();
  if (h2b == 0) {
    float* ps = partials + ((size_t)(b * NBLK + blockIdx.x) * C) * D;
#pragma unroll
    for (int c = 0; c < C; ++c)
      ps[c * D + d2b] = acc2b[c] + part[c * D + d2b];
  }
  if (wv == 0 && lane < C)
    pcnt[(b * NBLK + blockIdx.x) * C + lane] = cnt_run;
}

// ---------------------------------------------------------------------------
// K3: per dropped pixel: reduce the 32 L2-hot partials -> protoC on the fly,
// nearest proto (first-wins argmin == over the 12=2x6 duplicated list),
// patch x[b,:,px,py] = (proto_best . cls_w)/12 + cls_b directly.
// one wave per (b,p); lane owns d and d+64
// ---------------------------------------------------------------------------
__global__ void k_patch(const float* __restrict__ assp,
                        const float* __restrict__ partials,
                        const int* __restrict__ pcnt,
                        const float* __restrict__ cls_w,
                        const float* __restrict__ cls_b,
                        const int* __restrict__ px,
                        const int* __restrict__ py,
                        int P,
                        float* __restrict__ x) {
  int bp = blockIdx.x;
  int b = bp / P, p = bp % P;
  int hw = px[p] * W + py[p];
  int lane = threadIdx.x;                  // 64 threads = 1 wave
  const float* fbase = assp + ((size_t)b * D) * HWC + hw;

  float f0 = fbase[(size_t)lane * HWC];
  float f1 = fbase[(size_t)(lane + 64) * HWC];

  // reduce partial sums/counts over the 32 blocks of this batch
  float s0[C] = {0,0,0,0,0,0}, s1[C] = {0,0,0,0,0,0};
  int   cn[C] = {0,0,0,0,0,0};
  for (int blk = 0; blk < NBLK; ++blk) {
    const float* pp = partials + ((size_t)(b * NBLK + blk) * C) * D;
#pragma unroll
    for (int c = 0; c < C; ++c) {
      s0[c] += pp[c * D + lane];
      s1[c] += pp[c * D + lane + 64];
      cn[c] += pcnt[(b * NBLK + blk) * C + c];
    }
  }

  float pv0[C], pv1[C], ds[C];
#pragma unroll
  for (int c = 0; c < C; ++c) {
    float cnt = (float)cn[c];
    float q0 = (cnt > 0.f) ? s0[c] / (cnt + 1e-5f) : 0.f;
    float q1 = (cnt > 0.f) ? s1[c] / (cnt + 1e-5f) : 0.f;
    pv0[c] = q0; pv1[c] = q1;
    float e0 = q0 - f0, e1 = q1 - f1;
    float tt = e0 * e0 + e1 * e1;
#pragma unroll
    for (int off = 32; off >= 1; off >>= 1) tt += __shfl_xor(tt, off, 64);
    ds[c] = tt;                            // identical on all lanes
  }
  int best = 0; float bv = ds[0];          // first-wins ties == jnp.argmin
#pragma unroll
  for (int c = 1; c < C; ++c)
    if (ds[c] < bv) { bv = ds[c]; best = c; }

  float v0 = 0.f, v1 = 0.f;                // select without dynamic indexing
#pragma unroll
  for (int c = 0; c < C; ++c)
    if (best == c) { v0 = pv0[c]; v1 = pv1[c]; }

  float myx = 0.f;
#pragma unroll
  for (int c = 0; c < C; ++c) {
    float tt = v0 * cls_w[c * D + lane] + v1 * cls_w[c * D + lane + 64];
#pragma unroll
    for (int off = 32; off >= 1; off >>= 1) tt += __shfl_xor(tt, off, 64);
    float val = tt * (1.0f / 12.0f) + cls_b[c];
    if (lane == c) myx = val;
  }
  if (lane < C) x[((size_t)b * C + lane) * HWC + hw] = myx;
}

// ---------------------------------------------------------------------------
// K4: bilinear 4x upsample, numpy-matched weights (src = i*127/511 in double),
// 4 outputs / thread, float4 store
// ---------------------------------------------------------------------------
__global__ void k_up(const float* __restrict__ x, float* __restrict__ out) {
  int t = blockIdx.x * 256 + threadIdx.x;
  int i = t * 4;                               // 4 consecutive X, same row
  int X  = i & (WO - 1);
  int Y  = (i >> 9) & (HO - 1);
  int bc = i >> 18;

  double sy = (double)(Y * (H - 1)) / (double)(HO - 1);
  int y0 = (int)sy;
  float wy = (float)(sy - (double)y0);
  int y1 = y0 + 1; if (y1 > H - 1) y1 = H - 1;

  const float* r0 = x + (size_t)bc * HWC + y0 * W;
  const float* r1 = x + (size_t)bc * HWC + y1 * W;

  float o[4];
#pragma unroll
  for (int j = 0; j < 4; ++j) {
    int Xj = X + j;
    double sx = (double)(Xj * (W - 1)) / (double)(WO - 1);
    int x0 = (int)sx;
    float wx = (float)(sx - (double)x0);
    int x1 = x0 + 1; if (x1 > W - 1) x1 = W - 1;

    float v00 = r0[x0], v01 = r0[x1], v10 = r1[x0], v11 = r1[x1];
    o[j] = (1.f - wy) * ((1.f - wx) * v00 + wx * v01)
         +        wy  * ((1.f - wx) * v10 + wx * v11);
  }
  float4 o4; o4.x = o[0]; o4.y = o[1]; o4.z = o[2]; o4.w = o[3];
  *(float4*)(out + i) = o4;
}

} // namespace

extern "C" void kernel_launch(void* const* d_in, const int* in_sizes, int n_in,
                              void* d_out, int out_size, void* d_ws, size_t ws_size,
                              hipStream_t stream) {
  // inputs: assp, cls_w, cls_b, key_w, key_b, query_w, query_b, px, py
  const float* assp  = (const float*)d_in[0];
  const float* cls_w = (const float*)d_in[1];
  const float* cls_b = (const float*)d_in[2];
  const int*   px    = (const int*)d_in[7];
  const int*   py    = (const int*)d_in[8];
  const int    P     = in_sizes[7];             // 102

  // workspace layout (fully overwritten every call -> no memset needed)
  char* ws = (char*)d_ws;
  float* partials = (float*)ws;                         // B*NBLK*C*D = 1.57 MB
  int*   pcnt     = (int*)(ws + (size_t)B * NBLK * C * D * 4);   // 12 KB
  float* x        = (float*)(ws + (size_t)B * NBLK * C * D * 4 + B * NBLK * C * 4);

  float* out = (float*)d_out;

  k_fused<<<dim3(NBLK, B), 256, 0, stream>>>(assp, cls_w, cls_b,
                                             partials, pcnt, x);
  k_patch<<<B * P, 64, 0, stream>>>(assp, partials, pcnt, cls_w, cls_b,
                                    px, py, P, x);
  k_up<<<(B * C * HO * WO) / 1024, 256, 0, stream>>>(x, out);
}

// Round 5
// 281.384 us; speedup vs baseline: 1.0087x; 1.0087x over previous
//
#include <hip/hip_runtime.h>

namespace {

constexpr int B  = 16;
constexpr int D  = 128;
constexpr int C  = 6;
constexpr int H  = 128;
constexpr int W  = 128;
constexpr int HWC = H * W;          // 16384
constexpr int HO = 512, WO = 512;   // 4x upsample
constexpr int TILE = 64;            // pixels per LDS tile
constexpr int TPB  = 8;             // tiles per block (block owns 512 contiguous px)
constexpr int NBLK = HWC / (TILE * TPB);  // 32 blocks per batch image

// ---------------------------------------------------------------------------
// Fused K1+K2: one HBM pass over assp. SINGLE-buffered LDS tile (41 KB total
// -> 3 blocks/CU; R4's double-buffer at 73 KB -> 2 blocks/CU REGRESSED:
// inter-block wave overlap at 3 blocks/CU already hides staging latency).
// Per 64-px tile (XOR-swizzled, <=2-way banks for both access patterns):
//   2a: px-ownership dots -> argmax class (register) + x = dot/12 + bias
//   2b: d-ownership per-class sums, accumulated in registers across 8 tiles
// Block-end: plain stores to partials[b][blk][C][D] + pcnt[b][blk][C]
// (no atomics, no memset). softmax(...,1).mean(1) == 1/12 -> attention dead.
// ---------------------------------------------------------------------------
__global__ __launch_bounds__(256) void k_fused(const float* __restrict__ assp,
                                               const float* __restrict__ cls_w,
                                               const float* __restrict__ cls_b,
                                               float* __restrict__ partials,
                                               int* __restrict__ pcnt,
                                               float* __restrict__ x) {
  __shared__ float tile[D * TILE];      // 32 KB, [d*64 + (px ^ (d&62))]
  __shared__ float red[4 * C * TILE];   // red[q][c][px], 6 KB (reused as part[])
  __shared__ float ws[C * D];           // 3 KB
  __shared__ float bs[C];

  const int t  = threadIdx.x;
  const int b  = blockIdx.y;

  const int lane = t & 63;
  const int wv   = t >> 6;        // d-quarter for 2a, wave id
  const int d2b  = t & 127;       // d owned in 2b
  const int h2b  = t >> 7;        // px-half owned in 2b
  const int d1   = t >> 5;        // base d row for staging
  const int px2  = (t & 31) * 2;  // px pair for staging

  const float* base0 = assp + ((size_t)b * D) * HWC + blockIdx.x * (TILE * TPB);

  // prefetch tile 0 before ws staging — HBM loads in flight first
  float2 v[16];
#pragma unroll
  for (int j = 0; j < 16; ++j) {
    int d = d1 + 8 * j;
    v[j] = *(const float2*)(base0 + (size_t)d * HWC + px2);
  }

  for (int i = t; i < C * D; i += 256) ws[i] = cls_w[i];
  if (t < C) bs[t] = cls_b[t];

  float acc2b[C] = {0.f, 0.f, 0.f, 0.f, 0.f, 0.f};
  int   cnt_run  = 0;             // wave0 lane c accumulates count of class c

  __syncthreads();                // ws/bs ready

  for (int it = 0; it < TPB; ++it) {
    // ---- commit prefetched registers to LDS (swizzled) ----
#pragma unroll
    for (int j = 0; j < 16; ++j) {
      int d = d1 + 8 * j;
      *(float2*)&tile[d * TILE + (px2 ^ (d & 62))] = v[j];
    }
    __syncthreads();              // staging visible

    // ---- phase 2a: dots (px = lane, d-quarter = wv) ----
    {
      float a[C] = {0.f, 0.f, 0.f, 0.f, 0.f, 0.f};
#pragma unroll
      for (int dd = 0; dd < 32; ++dd) {
        int d = wv * 32 + dd;
        float vv = tile[d * TILE + (lane ^ (d & 62))];
#pragma unroll
        for (int c = 0; c < C; ++c) a[c] += vv * ws[c * D + d];
      }
#pragma unroll
      for (int c = 0; c < C; ++c) red[(wv * C + c) * TILE + lane] = a[c];
    }
    __syncthreads();

    // ---- finalize (replicated in all waves): class of px = lane ----
    int cls;
    {
      float s[C];
#pragma unroll
      for (int c = 0; c < C; ++c)
        s[c] = red[(0 * C + c) * TILE + lane] + red[(1 * C + c) * TILE + lane]
             + red[(2 * C + c) * TILE + lane] + red[(3 * C + c) * TILE + lane];
      float bv = s[0] + bs[0]; cls = 0;      // first-wins == jnp.argmax
#pragma unroll
      for (int c = 1; c < C; ++c) {
        float pv = s[c] + bs[c];
        if (pv > bv) { bv = pv; cls = c; }
      }
      if (wv == 0) {
        const float inv12 = 1.0f / 12.0f;
        int hw0 = blockIdx.x * (TILE * TPB) + it * TILE;
        float* xb = x + ((size_t)b * C) * HWC + hw0 + lane;
#pragma unroll
        for (int c = 0; c < C; ++c) xb[(size_t)c * HWC] = s[c] * inv12 + bs[c];
#pragma unroll
        for (int c = 0; c < C; ++c) {
          unsigned long long m = __ballot(cls == c);
          if (lane == c) cnt_run += (int)__popcll(m);
        }
      }
    }

    // ---- phase 2b: per-class sums (d = d2b, px-half = h2b) ----
#pragma unroll
    for (int i = 0; i < 32; ++i) {
      int px = h2b * 32 + i;
      float vv = tile[d2b * TILE + (px ^ (d2b & 62))];
      int c = __shfl(cls, px, 64);           // broadcast cls(px)
#pragma unroll
      for (int cc = 0; cc < C; ++cc) acc2b[cc] += (c == cc) ? vv : 0.f;
    }

    // ---- issue next tile's global loads, then sync before overwrite ----
    if (it + 1 < TPB) {
      const float* basen = base0 + (it + 1) * TILE;
#pragma unroll
      for (int j = 0; j < 16; ++j) {
        int d = d1 + 8 * j;
        v[j] = *(const float2*)(basen + (size_t)d * HWC + px2);
      }
    }
    __syncthreads();              // tile reads done before next staging
  }

  // ---- block epilogue: pair-reduce halves, plain stores (no atomics) ----
  float* part = red;                          // reuse (>=768 floats)
  if (h2b == 1) {
#pragma unroll
    for (int c = 0; c < C; ++c) part[c * D + d2b] = acc2b[c];
  }
  __syncthreads();
  if (h2b == 0) {
    float* ps = partials + ((size_t)(b * NBLK + blockIdx.x) * C) * D;
#pragma unroll
    for (int c = 0; c < C; ++c)
      ps[c * D + d2b] = acc2b[c] + part[c * D + d2b];
  }
  if (wv == 0 && lane < C)
    pcnt[(b * NBLK + blockIdx.x) * C + lane] = cnt_run;
}

// ---------------------------------------------------------------------------
// K3: per dropped pixel: reduce the 32 L2-hot partials -> protoC on the fly,
// nearest proto (first-wins argmin == over the 12=2x6 duplicated list),
// patch x[b,:,px,py] = (proto_best . cls_w)/12 + cls_b directly.
// one wave per (b,p); lane owns d and d+64
// ---------------------------------------------------------------------------
__global__ void k_patch(const float* __restrict__ assp,
                        const float* __restrict__ partials,
                        const int* __restrict__ pcnt,
                        const float* __restrict__ cls_w,
                        const float* __restrict__ cls_b,
                        const int* __restrict__ px,
                        const int* __restrict__ py,
                        int P,
                        float* __restrict__ x) {
  int bp = blockIdx.x;
  int b = bp / P, p = bp % P;
  int hw = px[p] * W + py[p];
  int lane = threadIdx.x;                  // 64 threads = 1 wave
  const float* fbase = assp + ((size_t)b * D) * HWC + hw;

  float f0 = fbase[(size_t)lane * HWC];
  float f1 = fbase[(size_t)(lane + 64) * HWC];

  // reduce partial sums/counts over the 32 blocks of this batch
  float s0[C] = {0,0,0,0,0,0}, s1[C] = {0,0,0,0,0,0};
  int   cn[C] = {0,0,0,0,0,0};
  for (int blk = 0; blk < NBLK; ++blk) {
    const float* pp = partials + ((size_t)(b * NBLK + blk) * C) * D;
#pragma unroll
    for (int c = 0; c < C; ++c) {
      s0[c] += pp[c * D + lane];
      s1[c] += pp[c * D + lane + 64];
      cn[c] += pcnt[(b * NBLK + blk) * C + c];
    }
  }

  float pv0[C], pv1[C], ds[C];
#pragma unroll
  for (int c = 0; c < C; ++c) {
    float cnt = (float)cn[c];
    float q0 = (cnt > 0.f) ? s0[c] / (cnt + 1e-5f) : 0.f;
    float q1 = (cnt > 0.f) ? s1[c] / (cnt + 1e-5f) : 0.f;
    pv0[c] = q0; pv1[c] = q1;
    float e0 = q0 - f0, e1 = q1 - f1;
    float tt = e0 * e0 + e1 * e1;
#pragma unroll
    for (int off = 32; off >= 1; off >>= 1) tt += __shfl_xor(tt, off, 64);
    ds[c] = tt;                            // identical on all lanes
  }
  int best = 0; float bv = ds[0];          // first-wins ties == jnp.argmin
#pragma unroll
  for (int c = 1; c < C; ++c)
    if (ds[c] < bv) { bv = ds[c]; best = c; }

  float v0 = 0.f, v1 = 0.f;                // select without dynamic indexing
#pragma unroll
  for (int c = 0; c < C; ++c)
    if (best == c) { v0 = pv0[c]; v1 = pv1[c]; }

  float myx = 0.f;
#pragma unroll
  for (int c = 0; c < C; ++c) {
    float tt = v0 * cls_w[c * D + lane] + v1 * cls_w[c * D + lane + 64];
#pragma unroll
    for (int off = 32; off >= 1; off >>= 1) tt += __shfl_xor(tt, off, 64);
    float val = tt * (1.0f / 12.0f) + cls_b[c];
    if (lane == c) myx = val;
  }
  if (lane < C) x[((size_t)b * C + lane) * HWC + hw] = myx;
}

// ---------------------------------------------------------------------------
// K4: bilinear 4x upsample, numpy-matched weights (src = i*127/511 in double),
// 4 outputs / thread, float4 store
// ---------------------------------------------------------------------------
__global__ void k_up(const float* __restrict__ x, float* __restrict__ out) {
  int t = blockIdx.x * 256 + threadIdx.x;
  int i = t * 4;                               // 4 consecutive X, same row
  int X  = i & (WO - 1);
  int Y  = (i >> 9) & (HO - 1);
  int bc = i >> 18;

  double sy = (double)(Y * (H - 1)) / (double)(HO - 1);
  int y0 = (int)sy;
  float wy = (float)(sy - (double)y0);
  int y1 = y0 + 1; if (y1 > H - 1) y1 = H - 1;

  const float* r0 = x + (size_t)bc * HWC + y0 * W;
  const float* r1 = x + (size_t)bc * HWC + y1 * W;

  float o[4];
#pragma unroll
  for (int j = 0; j < 4; ++j) {
    int Xj = X + j;
    double sx = (double)(Xj * (W - 1)) / (double)(WO - 1);
    int x0 = (int)sx;
    float wx = (float)(sx - (double)x0);
    int x1 = x0 + 1; if (x1 > W - 1) x1 = W - 1;

    float v00 = r0[x0], v01 = r0[x1], v10 = r1[x0], v11 = r1[x1];
    o[j] = (1.f - wy) * ((1.f - wx) * v00 + wx * v01)
         +        wy  * ((1.f - wx) * v10 + wx * v11);
  }
  float4 o4; o4.x = o[0]; o4.y = o[1]; o4.z = o[2]; o4.w = o[3];
  *(float4*)(out + i) = o4;
}

} // namespace

extern "C" void kernel_launch(void* const* d_in, const int* in_sizes, int n_in,
                              void* d_out, int out_size, void* d_ws, size_t ws_size,
                              hipStream_t stream) {
  // inputs: assp, cls_w, cls_b, key_w, key_b, query_w, query_b, px, py
  const float* assp  = (const float*)d_in[0];
  const float* cls_w = (const float*)d_in[1];
  const float* cls_b = (const float*)d_in[2];
  const int*   px    = (const int*)d_in[7];
  const int*   py    = (const int*)d_in[8];
  const int    P     = in_sizes[7];             // 102

  // workspace layout (fully overwritten every call -> no memset needed)
  char* ws = (char*)d_ws;
  float* partials = (float*)ws;                         // B*NBLK*C*D = 1.57 MB
  int*   pcnt     = (int*)(ws + (size_t)B * NBLK * C * D * 4);   // 12 KB
  float* x        = (float*)(ws + (size_t)B * NBLK * C * D * 4 + B * NBLK * C * 4);

  float* out = (float*)d_out;

  k_fused<<<dim3(NBLK, B), 256, 0, stream>>>(assp, cls_w, cls_b,
                                             partials, pcnt, x);
  k_patch<<<B * P, 64, 0, stream>>>(assp, partials, pcnt, cls_w, cls_b,
                                    px, py, P, x);
  k_up<<<(B * C * HO * WO) / 1024, 256, 0, stream>>>(x, out);
}